// Round 2
// baseline (177.693 us; speedup 1.0000x reference)
//
#include <hip/hip_runtime.h>
#include <math.h>

namespace {

// ============================================================================
// DIAGNOSTIC BUILD: main source loop replicated 8x in-kernel (result scaled
// by 0.125f, exact). Purpose: push es_main above the ~39.5us poison-fill so
// rocprof's top-k finally shows its counter row (VGPR_Count, VALUBusy,
// FETCH/WRITE = scratch-spill evidence, LDS conflicts, occupancy).
// Math is unchanged: a = 8*S, then *0.125f. An asm clobber on the per-pass
// target coords prevents cross-pass CSE/LICM (rule #17).
// ============================================================================

constexpr int   MTOT = 4096;       // total nodes
constexpr float H    = 0.1f;

// W_FACTORS = sqrt((0.5^2 + sigma^2)/2), sigma in {0.4, 0.8, 1.2, 1.6}
constexpr float W0 = 0.45276925690687087f;
constexpr float W1 = 0.66708320320631664f;
constexpr float W2 = 0.91923881554251174f;
constexpr float W3 = 1.18532695911296985f;

constexpr float KCOUL   = 14.399645478425669f;  // e*1e10/eps0/(4*pi)
constexpr float HALF_L1 = 2.8867513459481287f;  // 0.5*sqrt(3)/0.3
constexpr float SQRTPI  = 1.7724538509055159f;

// A&S 7.1.25 erf (|err|<=2.5e-5): erf(k d) = 1 - t(a1+a2 t+a3 t^2) * 2^(c2 d^2)
// with t = 1/(1 + pk d), pk = 0.47047*k, c2 = -k^2*log2(e).  k_r = 0.5/W_r.
constexpr float PK0 = 0.5195472f, PK1 = 0.3526314f, PK2 = 0.2559019f, PK3 = 0.1984558f;
constexpr float C20 = -1.7593842f, C21 = -0.8105028f, C22 = -0.4268329f, C23 = -0.2567073f;
constexpr float EA1 = 0.3480242f, EA2 = -0.0958798f, EA3 = 0.7478556f;
constexpr float RCP_H = 9.9999000f, RCP_HS2 = 7.0710178f, RCP_2H = 4.9999750f;

// KQ_r = -0.2*(2/sqrt(pi))*k_r : coefficient of the exp term in the dipole Gt.
constexpr float KQ0 = -0.24921720f, KQ1 = -0.16915128f, KQ2 = -0.12275067f, KQ3 = -0.09519549f;

// tier radii: near if any lane d<2; saturated (all erf==1) if all lanes d>7.03
constexpr float NEAR2 = 4.0f;
constexpr float SAT2  = 49.4f;

constexpr int NPASS = 8;                 // diagnostic replication factor
constexpr float INV_NPASS = 0.125f;      // exact power-of-2 scale

__device__ __forceinline__ float fast_rcp(float x)  { return __builtin_amdgcn_rcpf(x); }
__device__ __forceinline__ float fast_rsq(float x)  { return __builtin_amdgcn_rsqf(x); }
__device__ __forceinline__ float fast_exp2(float x) { return __builtin_amdgcn_exp2f(x); }

// q = erfc-part of A&S 7.1.25 (epilogue helper)
__device__ __forceinline__ float erf_q(float d, float d2, float pk, float c2) {
  float t = fast_rcp(__builtin_fmaf(d, pk, 1.0f));
  float poly = t * __builtin_fmaf(t, __builtin_fmaf(t, EA3, EA2), EA1);
  return poly * fast_exp2(d2 * c2);
}

// project (7 x 4) site-features S[j*4+r] -> 16 outputs
__device__ __forceinline__ float project_one(const float* S, int k) {
  if (k < 4) return S[k];
  int q = k - 4;
  int r = q / 3;
  int comp = q - 3 * r;
  int j1, j2;
  if (comp == 0)      { j1 = 2; j2 = 5; }
  else if (comp == 1) { j1 = 3; j2 = 6; }
  else                { j1 = 1; j2 = 4; }
  return HALF_L1 * (S[j1 * 4 + r] - S[j2 * 4 + r]);
}

__device__ __forceinline__ unsigned spread3(int v) {
  return (unsigned)((v & 1) | ((v & 2) << 2) | ((v & 4) << 4));
}

__global__ __launch_bounds__(896, 4) void es_main(
    const float* __restrict__ sf,   // (4096, 4)
    const float* __restrict__ pos,  // (4096, 3)
    float* __restrict__ out)        // [0:65536) features, [65536:131072) self_terms
{
  __shared__ float4   s_pos4[128];     // node centers (SORTED)
  __shared__ float4   s_chg4[128];     // prescaled charges {s0,5s3,5s1,5s2} (SORTED)
  __shared__ int      s_orig[128];     // sorted slot -> original node
  __shared__ unsigned s_key[128];
  __shared__ float4   s_part[8 * 112]; // per-chunk partial sums
  __shared__ float    s_feat[448];
  __shared__ float    s_self[448];

  const int b   = blockIdx.x;
  const int g   = b >> 3;    // graph
  const int nb  = b & 7;     // node-block (sorted space)
  const int tid = threadIdx.x;

  // ---- phase 1: node data + Morton keys ----
  float px = 0.f, py = 0.f, pz = 0.f;
  float4 myc = make_float4(0.f, 0.f, 0.f, 0.f);
  if (tid < 128) {
    const float* p = pos + (size_t)(g * 128 + tid) * 3;
    px = p[0]; py = p[1]; pz = p[2];
    const float4 s = ((const float4*)sf)[g * 128 + tid];
    myc = make_float4(s.x, 5.0f * s.w, 5.0f * s.y, 5.0f * s.z);
    int cx = (int)((px + 16.0f) * 0.25f); cx = (cx < 0) ? 0 : (cx > 7 ? 7 : cx);
    int cy = (int)((py + 16.0f) * 0.25f); cy = (cy < 0) ? 0 : (cy > 7 ? 7 : cy);
    int cz = (int)((pz + 16.0f) * 0.25f); cz = (cz < 0) ? 0 : (cz > 7 ? 7 : cz);
    unsigned mort = spread3(cx) | (spread3(cy) << 1) | (spread3(cz) << 2);
    s_key[tid] = (mort << 7) | (unsigned)tid;
  }
  __syncthreads();

  // ---- phase 2: rank-sort scatter ----
  if (tid < 128) {
    const unsigned mykey = s_key[tid];
    int rank = 0;
    for (int t = 0; t < 128; ++t) rank += (s_key[t] < mykey) ? 1 : 0;
    s_pos4[rank] = make_float4(px, py, pz, 0.0f);
    s_chg4[rank] = myc;
    s_orig[rank] = tid;
  }
  __syncthreads();

  // ---- per-thread target site (sorted space) ----
  const int site_local = tid % 112;
  const int chunk      = tid / 112;          // 0..7, 16 source nodes each
  const int sl   = nb * 112 + site_local;
  const int jown = (sl * 9363) >> 16;        // own node slot
  const int aoff = sl - jown * 7;

  const float4 cp = s_pos4[jown];
  const float tx = cp.x + ((aoff == 1) ? H : (aoff == 4) ? -H : 0.0f);
  const float ty = cp.y + ((aoff == 2) ? H : (aoff == 5) ? -H : 0.0f);
  const float tz = cp.z + ((aoff == 3) ? H : (aoff == 6) ? -H : 0.0f);

  float a0 = 0.f, a1 = 0.f, a2 = 0.f, a3 = 0.f, Ssat = 0.f;

  // exact per-subsite contribution, valid at ALL d (A&S 7.1.25 in registers)
  auto acc_full = [&](float d2raw, float c) {
    const float d2 = fmaxf(d2raw, 1e-12f);
    const float rd = fast_rsq(d2);
    const float d  = d2 * rd;
    const float cv = c * rd;
    const float t0 = fast_rcp(__builtin_fmaf(d, PK0, 1.0f));
    const float t1 = fast_rcp(__builtin_fmaf(d, PK1, 1.0f));
    const float t2 = fast_rcp(__builtin_fmaf(d, PK2, 1.0f));
    const float t3 = fast_rcp(__builtin_fmaf(d, PK3, 1.0f));
    const float q0 = t0 * __builtin_fmaf(t0, __builtin_fmaf(t0, EA3, EA2), EA1) * fast_exp2(d2 * C20);
    const float q1 = t1 * __builtin_fmaf(t1, __builtin_fmaf(t1, EA3, EA2), EA1) * fast_exp2(d2 * C21);
    const float q2 = t2 * __builtin_fmaf(t2, __builtin_fmaf(t2, EA3, EA2), EA1) * fast_exp2(d2 * C22);
    const float q3 = t3 * __builtin_fmaf(t3, __builtin_fmaf(t3, EA3, EA2), EA1) * fast_exp2(d2 * C23);
    a0 = __builtin_fmaf(cv, 1.0f - q0, a0);
    a1 = __builtin_fmaf(cv, 1.0f - q1, a1);
    a2 = __builtin_fmaf(cv, 1.0f - q2, a2);
    a3 = __builtin_fmaf(cv, 1.0f - q3, a3);
  };

  const int j0 = chunk * 16;

  // ======== DIAGNOSTIC: 8 replicated passes (see header comment) ========
  for (int pass = 0; pass < NPASS; ++pass) {
    // opaque copies: compiler cannot prove passes identical -> no cross-pass CSE
    float qx = tx, qy = ty, qz = tz;
    asm volatile("" : "+v"(qx), "+v"(qy), "+v"(qz));

    for (int jj = 0; jj < 16; ++jj) {
      const int j = j0 + jj;
      const float4 p4 = s_pos4[j];   // wave-uniform -> LDS broadcast
      const float4 c4 = s_chg4[j];
      const float vx = qx - p4.x;
      const float vy = qy - p4.y;
      const float vz = qz - p4.z;
      const float v2 = __builtin_fmaf(vx, vx, __builtin_fmaf(vy, vy, vz * vz));
      if (__any(v2 < NEAR2)) {
        // NEAR: exact 7-site path; own-site masking
        const float w2 = v2 + 0.01f;
        const bool own = (j == jown);
        acc_full(v2,                            (own & (aoff == 0)) ? 0.0f :  c4.x);
        acc_full(__builtin_fmaf(vx, -0.2f, w2), (own & (aoff == 1)) ? 0.0f :  c4.y);
        acc_full(__builtin_fmaf(vy, -0.2f, w2), (own & (aoff == 2)) ? 0.0f :  c4.z);
        acc_full(__builtin_fmaf(vz, -0.2f, w2), (own & (aoff == 3)) ? 0.0f :  c4.w);
        acc_full(__builtin_fmaf(vx,  0.2f, w2), (own & (aoff == 4)) ? 0.0f : -c4.y);
        acc_full(__builtin_fmaf(vy,  0.2f, w2), (own & (aoff == 5)) ? 0.0f : -c4.z);
        acc_full(__builtin_fmaf(vz,  0.2f, w2), (own & (aoff == 6)) ? 0.0f : -c4.w);
      } else if (__any(v2 < SAT2)) {
        // MID: monopole + dipole, fully analytic.
        const float rd  = fast_rsq(v2);
        const float d   = v2 * rd;
        const float dot = __builtin_fmaf(c4.y, vx, __builtin_fmaf(c4.z, vy, c4.w * vz));
        const float rd2 = rd * rd;
        const float P   = rd * __builtin_fmaf(0.2f * dot, rd2, c4.x);  // c0/d + 0.2*dot/d^3
        const float Qc  = dot * rd2;
        const float t0 = fast_rcp(__builtin_fmaf(d, PK0, 1.0f));
        const float t1 = fast_rcp(__builtin_fmaf(d, PK1, 1.0f));
        const float t2 = fast_rcp(__builtin_fmaf(d, PK2, 1.0f));
        const float t3 = fast_rcp(__builtin_fmaf(d, PK3, 1.0f));
        const float x0 = fast_exp2(v2 * C20);
        const float x1 = fast_exp2(v2 * C21);
        const float x2 = fast_exp2(v2 * C22);
        const float x3 = fast_exp2(v2 * C23);
        const float q0 = t0 * __builtin_fmaf(t0, __builtin_fmaf(t0, EA3, EA2), EA1) * x0;
        const float q1 = t1 * __builtin_fmaf(t1, __builtin_fmaf(t1, EA3, EA2), EA1) * x1;
        const float q2 = t2 * __builtin_fmaf(t2, __builtin_fmaf(t2, EA3, EA2), EA1) * x2;
        const float q3 = t3 * __builtin_fmaf(t3, __builtin_fmaf(t3, EA3, EA2), EA1) * x3;
        a0 = __builtin_fmaf(KQ0 * x0, Qc, __builtin_fmaf(-q0, P, a0 + P));
        a1 = __builtin_fmaf(KQ1 * x1, Qc, __builtin_fmaf(-q1, P, a1 + P));
        a2 = __builtin_fmaf(KQ2 * x2, Qc, __builtin_fmaf(-q2, P, a2 + P));
        a3 = __builtin_fmaf(KQ3 * x3, Qc, __builtin_fmaf(-q3, P, a3 + P));
      } else {
        // SAT: all lanes fully saturated -> analytic monopole + dipole
        const float rd  = fast_rsq(v2);
        const float dot = __builtin_fmaf(c4.y, vx, __builtin_fmaf(c4.z, vy, c4.w * vz));
        Ssat = __builtin_fmaf(c4.x, rd, Ssat);
        Ssat = __builtin_fmaf(0.2f * dot, rd * rd * rd, Ssat);
      }
    }
  }
  a0 += Ssat; a1 += Ssat; a2 += Ssat; a3 += Ssat;

  s_part[chunk * 112 + site_local] =
      make_float4(a0 * INV_NPASS, a1 * INV_NPASS, a2 * INV_NPASS, a3 * INV_NPASS);
  __syncthreads();

  // ---- reduce chunks + self term + own-node correction (cancels to +c_a*diag) ----
  if (tid < 448) {
    const int site = tid >> 2;   // 0..111 (sorted space)
    const int r    = tid & 3;
    const float* pf = (const float*)s_part;
    float tot = 0.f;
#pragma unroll
    for (int c = 0; c < 8; ++c) tot += pf[c * 448 + tid];

    const float w  = (r == 0) ? W0  : (r == 1) ? W1  : (r == 2) ? W2  : W3;
    const float pk = (r == 0) ? PK0 : (r == 1) ? PK1 : (r == 2) ? PK2 : PK3;
    const float c2 = (r == 0) ? C20 : (r == 1) ? C21 : (r == 2) ? C22 : C23;
    const float diag = fast_rcp(w * SQRTPI);
    const float ph1 = (1.f - erf_q(0.1f,        0.01f, pk, c2)) * RCP_H;
    const float ph2 = (1.f - erf_q(0.14142136f, 0.02f, pk, c2)) * RCP_HS2;
    const float ph3 = (1.f - erf_q(0.2f,        0.04f, pk, c2)) * RCP_2H;

    const int jn = (site * 9363) >> 16;
    const int ba = site - jn * 7;
    const float4 c4 = s_chg4[nb * 16 + jn];
    float selfSum = 0.f, ca = 0.f;
#pragma unroll
    for (int i = 0; i < 7; ++i) {
      const float ci = (i == 0) ?  c4.x : (i == 1) ?  c4.y : (i == 2) ?  c4.z :
                       (i == 3) ?  c4.w : (i == 4) ? -c4.y : (i == 5) ? -c4.z : -c4.w;
      float ph;
      if (i == ba)                             ph = diag;
      else if (i == 0 || ba == 0)              ph = ph1;
      else if ((i - ba == 3) || (ba - i == 3)) ph = ph3;
      else                                     ph = ph2;
      selfSum = __builtin_fmaf(ci, ph, selfSum);
      if (i == ba) ca = ci;
    }
    s_self[tid] = KCOUL * selfSum;
    s_feat[tid] = KCOUL * __builtin_fmaf(ca, diag, tot);
  }
  __syncthreads();

  // ---- projection + write (map sorted node -> original id) ----
  if (tid < 256) {
    const int node = tid >> 4;
    const int k    = tid & 15;
    const int m    = g * 128 + s_orig[nb * 16 + node];
    float vf = project_one(&s_feat[node * 28], k);
    float vs = project_one(&s_self[node * 28], k);
    out[m * 16 + k]             = vf;
    out[MTOT * 16 + m * 16 + k] = vs;
  }
}

} // namespace

extern "C" void kernel_launch(void* const* d_in, const int* in_sizes, int n_in,
                              void* d_out, int out_size, void* d_ws, size_t ws_size,
                              hipStream_t stream) {
  const float* sf  = (const float*)d_in[0];   // source_feats (4096,1,4)
  const float* pos = (const float*)d_in[1];   // node_positions (4096,3)
  float* out = (float*)d_out;
  es_main<<<256, 896, 0, stream>>>(sf, pos, out);
}

// Round 3
// 69.555 us; speedup vs baseline: 2.5547x; 2.5547x over previous
//
#include <hip/hip_runtime.h>
#include <math.h>

namespace {

// ============================================================================
// Target-side multipole collapse. Per target NODE (not site): accumulate
// potential + analytic gradient (4 radials) over all collapsed sources,
// branchlessly. l1 features use 2h*grad instead of the finite difference
// (error O(h^3) per source, same order as the accepted source-dipole
// truncation). Near pairs (center-d < 2.5) are compacted to an LDS list and
// processed wave-dense with the exact 7x7 site-site path. No Morton sort.
// Grid: 1024 blocks = 32 graphs x 32 groups (4 nodes). Block: 256 thr =
// 4 targets x 64 source-lanes.
// ============================================================================

constexpr int   MTOT = 4096;
constexpr float H    = 0.1f;

constexpr float W0 = 0.45276925690687087f;
constexpr float W1 = 0.66708320320631664f;
constexpr float W2 = 0.91923881554251174f;
constexpr float W3 = 1.18532695911296985f;

constexpr float KCOUL   = 14.399645478425669f;
constexpr float HALF_L1 = 2.8867513459481287f;
constexpr float SQRTPI  = 1.7724538509055159f;

// A&S 7.1.25: erf(k d) = 1 - t(a1+a2 t+a3 t^2) * 2^(c2 d^2), t=1/(1+pk d)
constexpr float PK[4] = {0.5195472f, 0.3526314f, 0.2559019f, 0.1984558f};
constexpr float C2[4] = {-1.7593842f, -0.8105028f, -0.4268329f, -0.2567073f};
constexpr float EA1 = 0.3480242f, EA2 = -0.0958798f, EA3 = 0.7478556f;
constexpr float RCP_H = 9.9999000f, RCP_HS2 = 7.0710178f, RCP_2H = 4.9999750f;

// KA_r = 2 k_r / sqrt(pi)   (dE/dd = KA * 2^(C2 d^2));  K2X_r = 2 k_r^2
constexpr float KA[4]  = {1.2460860f, 0.84575637f, 0.61375334f, 0.47597746f};
constexpr float K2X[4] = {2.4390243f, 1.1235959f, 0.59171598f, 0.35587189f};

constexpr float NEAR2   = 6.25f;   // exact path when center-d < 2.5
constexpr int   NEARCAP = 256;

__device__ __forceinline__ float fast_rcp(float x)  { return __builtin_amdgcn_rcpf(x); }
__device__ __forceinline__ float fast_rsq(float x)  { return __builtin_amdgcn_rsqf(x); }
__device__ __forceinline__ float fast_exp2(float x) { return __builtin_amdgcn_exp2f(x); }

__device__ __forceinline__ float erf_q(float d, float d2, float pk, float c2) {
  float t = fast_rcp(__builtin_fmaf(d, pk, 1.0f));
  float poly = t * __builtin_fmaf(t, __builtin_fmaf(t, EA3, EA2), EA1);
  return poly * fast_exp2(d2 * c2);
}

__device__ __forceinline__ float project_one(const float* S, int k) {
  if (k < 4) return S[k];
  int q = k - 4;
  int r = q / 3;
  int comp = q - 3 * r;
  int j1, j2;
  if (comp == 0)      { j1 = 2; j2 = 5; }
  else if (comp == 1) { j1 = 3; j2 = 6; }
  else                { j1 = 1; j2 = 4; }
  return HALF_L1 * (S[j1 * 4 + r] - S[j2 * 4 + r]);
}

// offset component of sub-site a (0..6): (+H on axis a-1, -H on axis a-4)
__device__ __forceinline__ float offx(int a) { return (a == 1) ? H : (a == 4) ? -H : 0.0f; }
__device__ __forceinline__ float offy(int a) { return (a == 2) ? H : (a == 5) ? -H : 0.0f; }
__device__ __forceinline__ float offz(int a) { return (a == 3) ? H : (a == 6) ? -H : 0.0f; }

__global__ __launch_bounds__(256, 4) void es_main(
    const float* __restrict__ sf,   // (4096, 4)
    const float* __restrict__ pos,  // (4096, 3)
    float* __restrict__ out)        // [0:65536) features, [65536:131072) self_terms
{
  __shared__ float4 s_pos4[128];
  __shared__ float4 s_chg4[128];      // {s0, 5*s3, 5*s1, 5*s2}
  __shared__ float  s_red[4][16];     // per-node: pot[4], gx[4], gy[4], gz[4]
  __shared__ float  s_nearS[4][7][4]; // near-pair exact site contributions
  __shared__ int    s_nearI[NEARCAP];
  __shared__ int    s_ncnt;
  __shared__ float  s_feat[4 * 28];
  __shared__ float  s_self[4 * 28];

  const int b   = blockIdx.x;
  const int g   = b >> 5;    // graph
  const int grp = b & 31;    // node group (4 nodes)
  const int tid = threadIdx.x;
  const int t   = tid >> 6;  // target node 0..3 (= wave id)
  const int c   = tid & 63;  // source lane

  // ---- stage graph node data ----
  if (tid < 128) {
    const float* p = pos + (size_t)(g * 128 + tid) * 3;
    const float4 s = ((const float4*)sf)[g * 128 + tid];
    s_pos4[tid] = make_float4(p[0], p[1], p[2], 0.0f);
    s_chg4[tid] = make_float4(s.x, 5.0f * s.w, 5.0f * s.y, 5.0f * s.z);
  }
  if (tid < 112) ((float*)s_nearS)[tid] = 0.0f;
  if (tid == 0) s_ncnt = 0;
  __syncthreads();

  const int own = grp * 4 + t;
  const float4 cp = s_pos4[own];

  float acc[16];
#pragma unroll
  for (int k = 0; k < 16; ++k) acc[k] = 0.0f;

  // ---- phase 1: branchless multipole pot+grad over 2 sources/lane ----
#pragma unroll
  for (int si = 0; si < 2; ++si) {
    const int j = c + 64 * si;
    if (j != own) {
      const float4 p4 = s_pos4[j];
      const float4 c4 = s_chg4[j];
      const float vx = cp.x - p4.x;
      const float vy = cp.y - p4.y;
      const float vz = cp.z - p4.z;
      const float d2 = __builtin_fmaf(vx, vx, __builtin_fmaf(vy, vy, vz * vz));
      if (d2 < NEAR2) {
        int slot = atomicAdd(&s_ncnt, 1);
        if (slot < NEARCAP) s_nearI[slot] = (t << 8) | j;
      } else {
        const float rd  = fast_rsq(d2);
        const float d   = d2 * rd;
        const float rd2 = rd * rd;
        const float rd3 = rd2 * rd;
        const float rd4 = rd2 * rd2;
        const float S3  = 3.0f * rd3;
        const float S4  = 3.0f * rd4;
        const float dot = __builtin_fmaf(c4.y, vx, __builtin_fmaf(c4.z, vy, c4.w * vz));
        const float dp  = 0.2f * dot;   // = p . v
        const float c0  = c4.x;
#pragma unroll
        for (int r = 0; r < 4; ++r) {
          const float tt = fast_rcp(__builtin_fmaf(d, PK[r], 1.0f));
          const float X  = fast_exp2(d2 * C2[r]);
          const float q  = tt * __builtin_fmaf(tt, __builtin_fmaf(tt, EA3, EA2), EA1) * X;
          const float E  = 1.0f - q;
          const float A  = KA[r] * X;
          const float gv = E * rd;               // erf/d
          const float gp = (A - gv) * rd;        // d/dd (erf/d)
          const float Bv = -gp * rd;             // E/d^3 - A/d^2
          const float h1 = __builtin_fmaf(K2X[r], rd, S3);
          const float Bp = __builtin_fmaf(A, h1, -(E * S4));   // dBv/dd
          acc[r] = __builtin_fmaf(dp, Bv, __builtin_fmaf(c0, gv, acc[r]));
          const float sv  = __builtin_fmaf(dp, Bp, c0 * gp) * rd;  // radial coeff * (1/d)
          const float B02 = 0.2f * Bv;
          acc[4 + r]  = __builtin_fmaf(sv, vx, __builtin_fmaf(B02, c4.y, acc[4 + r]));
          acc[8 + r]  = __builtin_fmaf(sv, vy, __builtin_fmaf(B02, c4.z, acc[8 + r]));
          acc[12 + r] = __builtin_fmaf(sv, vz, __builtin_fmaf(B02, c4.w, acc[12 + r]));
        }
      }
    }
  }

  // ---- full-wave reduction over the 64 source lanes ----
#pragma unroll
  for (int k = 0; k < 16; ++k) {
    float v = acc[k];
    v += __shfl_xor(v, 1);
    v += __shfl_xor(v, 2);
    v += __shfl_xor(v, 4);
    v += __shfl_xor(v, 8);
    v += __shfl_xor(v, 16);
    v += __shfl_xor(v, 32);
    acc[k] = v;
  }
  if (c == 0) {
#pragma unroll
    for (int k = 0; k < 16; ++k) s_red[t][k] = acc[k];
  }
  __syncthreads();

  // ---- phase 2: near list, exact 7x7, wave-dense ----
  const int N = (s_ncnt < NEARCAP) ? s_ncnt : NEARCAP;
  for (int e = t; e < N; e += 4) {
    const int ent = s_nearI[e];
    const int tt  = ent >> 8;
    const int j   = ent & 127;
    const int a   = c >> 3;        // target sub-site 0..7 (7 = inactive)
    const int i   = c & 7;         // source sub-site 0..7 (7 = inactive)
    const bool act = (a < 7) && (i < 7);
    const float4 tp = s_pos4[grp * 4 + tt];
    const float4 p4 = s_pos4[j];
    const float4 c4 = s_chg4[j];
    const float ci = !act ? 0.0f :
                     (i == 0) ?  c4.x : (i == 1) ?  c4.y : (i == 2) ?  c4.z :
                     (i == 3) ?  c4.w : (i == 4) ? -c4.y : (i == 5) ? -c4.z : -c4.w;
    const float sx = tp.x - p4.x + offx(a) - offx(i);
    const float sy = tp.y - p4.y + offy(a) - offy(i);
    const float sz = tp.z - p4.z + offz(a) - offz(i);
    const float d2 = fmaxf(__builtin_fmaf(sx, sx, __builtin_fmaf(sy, sy, sz * sz)), 1e-12f);
    const float rd = fast_rsq(d2);
    const float d  = d2 * rd;
    const float cv = ci * rd;
    float vr[4];
#pragma unroll
    for (int r = 0; r < 4; ++r) {
      const float tt2 = fast_rcp(__builtin_fmaf(d, PK[r], 1.0f));
      const float q   = tt2 * __builtin_fmaf(tt2, __builtin_fmaf(tt2, EA3, EA2), EA1)
                            * fast_exp2(d2 * C2[r]);
      vr[r] = cv * (1.0f - q);
    }
    // reduce over source sub-site i (8-lane groups; i==7 contributes 0)
#pragma unroll
    for (int r = 0; r < 4; ++r) {
      float v = vr[r];
      v += __shfl_xor(v, 1);
      v += __shfl_xor(v, 2);
      v += __shfl_xor(v, 4);
      vr[r] = v;
    }
    if (i == 0 && a < 7) {
#pragma unroll
      for (int r = 0; r < 4; ++r) atomicAdd(&s_nearS[tt][a][r], vr[r]);
    }
  }
  __syncthreads();

  // ---- epilogue: site values (pot + o.grad + near) + self terms ----
  if (tid < 112) {
    const int node = tid / 28;          // 0..3
    const int rem  = tid - node * 28;
    const int a    = rem >> 2;          // sub-site 0..6
    const int r    = rem & 3;           // radial

    const float pot = s_red[node][r];
    const float gx  = s_red[node][4 + r];
    const float gy  = s_red[node][8 + r];
    const float gz  = s_red[node][12 + r];
    const float od  = (a == 1) ?  H * gx : (a == 2) ?  H * gy : (a == 3) ?  H * gz :
                      (a == 4) ? -H * gx : (a == 5) ? -H * gy : (a == 6) ? -H * gz : 0.0f;
    const float mid = pot + od + s_nearS[node][a][r];

    const float w  = (r == 0) ? W0 : (r == 1) ? W1 : (r == 2) ? W2 : W3;
    const float pk = PK[r];
    const float c2 = C2[r];
    const float diag = fast_rcp(w * SQRTPI);
    const float ph1 = (1.f - erf_q(0.1f,        0.01f, pk, c2)) * RCP_H;
    const float ph2 = (1.f - erf_q(0.14142136f, 0.02f, pk, c2)) * RCP_HS2;
    const float ph3 = (1.f - erf_q(0.2f,        0.04f, pk, c2)) * RCP_2H;

    const float4 c4 = s_chg4[grp * 4 + node];
    float selfSum = 0.f;
#pragma unroll
    for (int i = 0; i < 7; ++i) {
      const float ci = (i == 0) ?  c4.x : (i == 1) ?  c4.y : (i == 2) ?  c4.z :
                       (i == 3) ?  c4.w : (i == 4) ? -c4.y : (i == 5) ? -c4.z : -c4.w;
      float ph;
      if (i == a)                            ph = diag;
      else if (i == 0 || a == 0)             ph = ph1;
      else if ((i - a == 3) || (a - i == 3)) ph = ph3;
      else                                   ph = ph2;
      selfSum = __builtin_fmaf(ci, ph, selfSum);
    }
    const float sv = KCOUL * selfSum;
    s_self[tid] = sv;
    s_feat[tid] = __builtin_fmaf(KCOUL, mid, sv);   // features = sfeat + sself (projected)
  }
  __syncthreads();

  // ---- projection + write (original node order; no sort) ----
  if (tid < 64) {
    const int node = tid >> 4;
    const int k    = tid & 15;
    const int m    = g * 128 + grp * 4 + node;
    out[m * 16 + k]             = project_one(&s_feat[node * 28], k);
    out[MTOT * 16 + m * 16 + k] = project_one(&s_self[node * 28], k);
  }
}

} // namespace

extern "C" void kernel_launch(void* const* d_in, const int* in_sizes, int n_in,
                              void* d_out, int out_size, void* d_ws, size_t ws_size,
                              hipStream_t stream) {
  const float* sf  = (const float*)d_in[0];   // source_feats (4096,1,4)
  const float* pos = (const float*)d_in[1];   // node_positions (4096,3)
  float* out = (float*)d_out;
  es_main<<<1024, 256, 0, stream>>>(sf, pos, out);
}